// Round 8
// baseline (652.055 us; speedup 1.0000x reference)
//
#include <hip/hip_runtime.h>

// OrdinalWeightedError: out = sum((interp_pcnl(x_i) - pcnl[t_i])^2 * w[t_i]) / sum(w[t_i])
// C = 5. Memory-bound streaming reduction over input(f32,N) + target(i32,N) = 128 MiB.
// Round 8: reduce path FROZEN from r7 (nt loads, J=4, 4096 blocks, ~3.6 TB/s read —
// at/above the best measured read rate on this chip; ILP/occupancy surface was flat).
// Change: fuse the final reduction via last-block-done (threadfence + device-scope
// atomicAdd counter), dropping the second kernel launch. Counter init: 4-byte
// hipMemsetAsync (graph-legal). dur_us model: ~83 us harness reset + reduce + overhead.
// NO __launch_bounds__ min-waves arg (r1/r2: ",8" clamped VGPR to 32 -> full spill).

#define OWE_T 256
#define OWE_J 4   // float4 chunks per thread -> 16 elements/thread
#define OWE_C 5

typedef float f32x4 __attribute__((ext_vector_type(4)));
typedef int   i32x4 __attribute__((ext_vector_type(4)));

__device__ __forceinline__ void owe_process(float xv, int tv,
                                            const float2* __restrict__ s_tab,
                                            float& acc_num, float& acc_den)
{
    float f  = floorf(xv);
    float fr = xv - f;

    float v0 = f;
    float v1 = f + 1.0f;
    int   c0 = min(max((int)v0, 0), OWE_C - 1);   // v_med3
    int   c1 = min(max((int)v1, 0), OWE_C - 1);
    bool  r0 = (v0 >= 0.0f) && (v0 <= (float)(OWE_C - 1));
    bool  r1 = (v1 >= 0.0f) && (v1 <= (float)(OWE_C - 1));

    float pf = r0 ? s_tab[c0].x : v0 * 0.25f;   // x/(C-1) == x*0.25 exactly
    float pc = r1 ? s_tab[c1].x : v1 * 0.25f;

    float  ip = fmaf(pc - pf, fr, pf);
    float2 tw = s_tab[tv];                      // one ds_read_b64: {pcnl[t], w[t]}
    float  diff = ip - tw.x;
    acc_num = fmaf(diff * diff, tw.y, acc_num);
    acc_den += tw.y;
}

__global__ __launch_bounds__(OWE_T) void owe_reduce_kernel(
    const f32x4* __restrict__ in4,
    const i32x4* __restrict__ tg4,
    const float* __restrict__ weight,
    const float* __restrict__ dist,
    float2*      __restrict__ partials,
    int*         __restrict__ counter,
    const float* __restrict__ input,
    const int*   __restrict__ target,
    int n, int n4, int grid_n,
    float*       __restrict__ out)
{
    __shared__ float2 s_tab[8];
    __shared__ float2 s_part[OWE_T / 64];
    __shared__ double s_n[OWE_T / 64], s_d[OWE_T / 64];
    __shared__ int    s_last;

    if (threadIdx.x == 0) {
        // pcnl[i] = (2*cs[i] - d[i] - d[0]) / (2*cs[C-1] - d[0] - d[C-1])
        float d0 = dist[0], d1 = dist[1], d2 = dist[2], d3 = dist[3], d4 = dist[4];
        float cs1 = d0 + d1, cs2 = cs1 + d2, cs3 = cs2 + d3, cs4 = cs3 + d4;
        float inv = 1.0f / (2.0f * cs4 - d0 - d4);
        s_tab[0] = make_float2((2.0f * d0  - d0 - d0) * inv, weight[0]);
        s_tab[1] = make_float2((2.0f * cs1 - d1 - d0) * inv, weight[1]);
        s_tab[2] = make_float2((2.0f * cs2 - d2 - d0) * inv, weight[2]);
        s_tab[3] = make_float2((2.0f * cs3 - d3 - d0) * inv, weight[3]);
        s_tab[4] = make_float2((2.0f * cs4 - d4 - d0) * inv, weight[4]);
    }
    __syncthreads();

    float acc_num = 0.0f, acc_den = 0.0f;

    const int base = blockIdx.x * (OWE_T * OWE_J) + threadIdx.x;

    if ((blockIdx.x + 1) * (OWE_T * OWE_J) <= n4) {
        // fast path: straight-line, 8 nt-loads in flight, named regs only
        f32x4 x0 = __builtin_nontemporal_load(&in4[base + 0 * OWE_T]);
        i32x4 t0 = __builtin_nontemporal_load(&tg4[base + 0 * OWE_T]);
        f32x4 x1 = __builtin_nontemporal_load(&in4[base + 1 * OWE_T]);
        i32x4 t1 = __builtin_nontemporal_load(&tg4[base + 1 * OWE_T]);
        f32x4 x2 = __builtin_nontemporal_load(&in4[base + 2 * OWE_T]);
        i32x4 t2 = __builtin_nontemporal_load(&tg4[base + 2 * OWE_T]);
        f32x4 x3 = __builtin_nontemporal_load(&in4[base + 3 * OWE_T]);
        i32x4 t3 = __builtin_nontemporal_load(&tg4[base + 3 * OWE_T]);

        owe_process(x0.x, t0.x, s_tab, acc_num, acc_den);
        owe_process(x0.y, t0.y, s_tab, acc_num, acc_den);
        owe_process(x0.z, t0.z, s_tab, acc_num, acc_den);
        owe_process(x0.w, t0.w, s_tab, acc_num, acc_den);
        owe_process(x1.x, t1.x, s_tab, acc_num, acc_den);
        owe_process(x1.y, t1.y, s_tab, acc_num, acc_den);
        owe_process(x1.z, t1.z, s_tab, acc_num, acc_den);
        owe_process(x1.w, t1.w, s_tab, acc_num, acc_den);
        owe_process(x2.x, t2.x, s_tab, acc_num, acc_den);
        owe_process(x2.y, t2.y, s_tab, acc_num, acc_den);
        owe_process(x2.z, t2.z, s_tab, acc_num, acc_den);
        owe_process(x2.w, t2.w, s_tab, acc_num, acc_den);
        owe_process(x3.x, t3.x, s_tab, acc_num, acc_den);
        owe_process(x3.y, t3.y, s_tab, acc_num, acc_den);
        owe_process(x3.z, t3.z, s_tab, acc_num, acc_den);
        owe_process(x3.w, t3.w, s_tab, acc_num, acc_den);
    } else {
        // tail block (only when n4 % (T*J) != 0)
        for (int j = 0; j < OWE_J; ++j) {
            int idx = base + j * OWE_T;
            if (idx < n4) {
                f32x4 x = __builtin_nontemporal_load(&in4[idx]);
                i32x4 t = __builtin_nontemporal_load(&tg4[idx]);
                owe_process(x.x, t.x, s_tab, acc_num, acc_den);
                owe_process(x.y, t.y, s_tab, acc_num, acc_den);
                owe_process(x.z, t.z, s_tab, acc_num, acc_den);
                owe_process(x.w, t.w, s_tab, acc_num, acc_den);
            }
        }
    }

    // wave64 reduction
    #pragma unroll
    for (int off = 32; off > 0; off >>= 1) {
        acc_num += __shfl_down(acc_num, off);
        acc_den += __shfl_down(acc_den, off);
    }
    int lane = threadIdx.x & 63;
    int wid  = threadIdx.x >> 6;
    if (lane == 0) s_part[wid] = make_float2(acc_num, acc_den);
    __syncthreads();
    if (threadIdx.x == 0) {
        float n_ = 0.0f, d_ = 0.0f;
        #pragma unroll
        for (int w = 0; w < OWE_T / 64; ++w) { n_ += s_part[w].x; d_ += s_part[w].y; }
        partials[blockIdx.x] = make_float2(n_, d_);
    }

    // ---- fused finalization: last block to arrive reduces all partials ----
    __threadfence();                      // publish our partial device-wide
    if (threadIdx.x == 0) {
        int old = atomicAdd(counter, 1);  // device-scope by default (m20)
        s_last = (old == grid_n - 1);
    }
    __syncthreads();
    if (!s_last) return;

    __threadfence();                      // acquire: all partials now visible
    double nn = 0.0, dd = 0.0;
    for (int i = threadIdx.x; i < grid_n; i += OWE_T) {
        float2 p = partials[i];
        nn += (double)p.x;
        dd += (double)p.y;
    }
    #pragma unroll
    for (int off = 32; off > 0; off >>= 1) {
        nn += __shfl_down(nn, off);
        dd += __shfl_down(dd, off);
    }
    if (lane == 0) { s_n[wid] = nn; s_d[wid] = dd; }
    __syncthreads();
    if (threadIdx.x == 0) {
        double N = 0.0, D = 0.0;
        #pragma unroll
        for (int w = 0; w < OWE_T / 64; ++w) { N += s_n[w]; D += s_d[w]; }
        // leftover elements (n % 4 != 0) — none for N=2^24, kept for generality
        int rem_start = (n / 4) * 4;
        if (rem_start < n) {
            float tab0 = s_tab[0].x, tab1 = s_tab[1].x, tab2 = s_tab[2].x,
                  tab3 = s_tab[3].x, tab4 = s_tab[4].x;
            float pcnl[5] = {tab0, tab1, tab2, tab3, tab4};
            for (int i = rem_start; i < n; ++i) {
                float xv = input[i];
                int   tv = target[i];
                float f  = floorf(xv);
                float v0 = f, v1 = f + 1.0f;
                int c0 = min(max((int)v0, 0), 4), c1 = min(max((int)v1, 0), 4);
                float pf = (v0 >= 0.0f && v0 <= 4.0f) ? pcnl[c0] : v0 * 0.25f;
                float pc = (v1 >= 0.0f && v1 <= 4.0f) ? pcnl[c1] : v1 * 0.25f;
                float ip = pf + (pc - pf) * (xv - f);
                float diff = ip - pcnl[tv];
                float w = s_tab[tv].y;
                N += (double)(diff * diff * w);
                D += (double)w;
            }
        }
        out[0] = (float)(N / D);
    }
}

extern "C" void kernel_launch(void* const* d_in, const int* in_sizes, int n_in,
                              void* d_out, int out_size, void* d_ws, size_t ws_size,
                              hipStream_t stream) {
    const float* input  = (const float*)d_in[0];
    const int*   target = (const int*)  d_in[1];
    const float* weight = (const float*)d_in[2];
    const float* dist   = (const float*)d_in[3];
    float*  out      = (float*)d_out;
    float2* partials = (float2*)d_ws;

    int n  = in_sizes[0];
    int n4 = n / 4;
    int grid = (n4 + OWE_T * OWE_J - 1) / (OWE_T * OWE_J);   // 4096 for N=2^24

    // counter lives right after the partials array in ws
    int* counter = (int*)((char*)d_ws + (size_t)grid * sizeof(float2));

    hipMemsetAsync(counter, 0, sizeof(int), stream);         // graph-legal
    owe_reduce_kernel<<<grid, OWE_T, 0, stream>>>(
        (const f32x4*)input, (const i32x4*)target, weight, dist,
        partials, counter, input, target, n, n4, grid, out);
}

// Round 9
// 146.686 us; speedup vs baseline: 4.4452x; 4.4452x over previous
//
#include <hip/hip_runtime.h>

// OrdinalWeightedError: out = sum((interp_pcnl(x_i) - pcnl[t_i])^2 * w[t_i]) / sum(w[t_i])
// C = 5. Memory-bound streaming reduction over input(f32,N) + target(i32,N) = 128 MiB.
// Round 9: REVERT to r7 exactly (proven 143.7 us). r8's last-block fusion cost +500 us:
// __threadfence() device-scope = per-block L2 writeback across 8 non-coherent XCDs
// (4096 fences serialized, kernel at 0.48 GB/s for 544 us). Two-kernel form is optimal.
// Reduce path: nt loads (read-once; default policy capped at 3.0-3.2 TB/s across all
// ILP/occupancy shapes, nt -> ~3.7 TB/s), J=4, 4096 blocks, VGPR~52.
// NO __launch_bounds__ min-waves arg (r1/r2: ",8" clamped VGPR to 32 -> full spill).

#define OWE_T 256
#define OWE_J 4   // float4 chunks per thread -> 16 elements/thread
#define OWE_C 5

typedef float f32x4 __attribute__((ext_vector_type(4)));
typedef int   i32x4 __attribute__((ext_vector_type(4)));

__device__ __forceinline__ void owe_process(float xv, int tv,
                                            const float2* __restrict__ s_tab,
                                            float& acc_num, float& acc_den)
{
    float f  = floorf(xv);
    float fr = xv - f;

    float v0 = f;
    float v1 = f + 1.0f;
    int   c0 = min(max((int)v0, 0), OWE_C - 1);   // v_med3
    int   c1 = min(max((int)v1, 0), OWE_C - 1);
    bool  r0 = (v0 >= 0.0f) && (v0 <= (float)(OWE_C - 1));
    bool  r1 = (v1 >= 0.0f) && (v1 <= (float)(OWE_C - 1));

    float pf = r0 ? s_tab[c0].x : v0 * 0.25f;   // x/(C-1) == x*0.25 exactly
    float pc = r1 ? s_tab[c1].x : v1 * 0.25f;

    float  ip = fmaf(pc - pf, fr, pf);
    float2 tw = s_tab[tv];                      // one ds_read_b64: {pcnl[t], w[t]}
    float  diff = ip - tw.x;
    acc_num = fmaf(diff * diff, tw.y, acc_num);
    acc_den += tw.y;
}

__global__ __launch_bounds__(OWE_T) void owe_reduce_kernel(
    const f32x4* __restrict__ in4,
    const i32x4* __restrict__ tg4,
    const float* __restrict__ weight,
    const float* __restrict__ dist,
    float2*      __restrict__ partials,
    int n4)
{
    __shared__ float2 s_tab[8];
    __shared__ float2 s_part[OWE_T / 64];

    if (threadIdx.x == 0) {
        // pcnl[i] = (2*cs[i] - d[i] - d[0]) / (2*cs[C-1] - d[0] - d[C-1])
        float d0 = dist[0], d1 = dist[1], d2 = dist[2], d3 = dist[3], d4 = dist[4];
        float cs1 = d0 + d1, cs2 = cs1 + d2, cs3 = cs2 + d3, cs4 = cs3 + d4;
        float inv = 1.0f / (2.0f * cs4 - d0 - d4);
        s_tab[0] = make_float2((2.0f * d0  - d0 - d0) * inv, weight[0]);
        s_tab[1] = make_float2((2.0f * cs1 - d1 - d0) * inv, weight[1]);
        s_tab[2] = make_float2((2.0f * cs2 - d2 - d0) * inv, weight[2]);
        s_tab[3] = make_float2((2.0f * cs3 - d3 - d0) * inv, weight[3]);
        s_tab[4] = make_float2((2.0f * cs4 - d4 - d0) * inv, weight[4]);
    }
    __syncthreads();

    float acc_num = 0.0f, acc_den = 0.0f;

    const int base = blockIdx.x * (OWE_T * OWE_J) + threadIdx.x;

    if ((blockIdx.x + 1) * (OWE_T * OWE_J) <= n4) {
        // fast path: straight-line, 8 nt-loads in flight, named regs only
        f32x4 x0 = __builtin_nontemporal_load(&in4[base + 0 * OWE_T]);
        i32x4 t0 = __builtin_nontemporal_load(&tg4[base + 0 * OWE_T]);
        f32x4 x1 = __builtin_nontemporal_load(&in4[base + 1 * OWE_T]);
        i32x4 t1 = __builtin_nontemporal_load(&tg4[base + 1 * OWE_T]);
        f32x4 x2 = __builtin_nontemporal_load(&in4[base + 2 * OWE_T]);
        i32x4 t2 = __builtin_nontemporal_load(&tg4[base + 2 * OWE_T]);
        f32x4 x3 = __builtin_nontemporal_load(&in4[base + 3 * OWE_T]);
        i32x4 t3 = __builtin_nontemporal_load(&tg4[base + 3 * OWE_T]);

        owe_process(x0.x, t0.x, s_tab, acc_num, acc_den);
        owe_process(x0.y, t0.y, s_tab, acc_num, acc_den);
        owe_process(x0.z, t0.z, s_tab, acc_num, acc_den);
        owe_process(x0.w, t0.w, s_tab, acc_num, acc_den);
        owe_process(x1.x, t1.x, s_tab, acc_num, acc_den);
        owe_process(x1.y, t1.y, s_tab, acc_num, acc_den);
        owe_process(x1.z, t1.z, s_tab, acc_num, acc_den);
        owe_process(x1.w, t1.w, s_tab, acc_num, acc_den);
        owe_process(x2.x, t2.x, s_tab, acc_num, acc_den);
        owe_process(x2.y, t2.y, s_tab, acc_num, acc_den);
        owe_process(x2.z, t2.z, s_tab, acc_num, acc_den);
        owe_process(x2.w, t2.w, s_tab, acc_num, acc_den);
        owe_process(x3.x, t3.x, s_tab, acc_num, acc_den);
        owe_process(x3.y, t3.y, s_tab, acc_num, acc_den);
        owe_process(x3.z, t3.z, s_tab, acc_num, acc_den);
        owe_process(x3.w, t3.w, s_tab, acc_num, acc_den);
    } else {
        // tail block (only when n4 % (T*J) != 0)
        for (int j = 0; j < OWE_J; ++j) {
            int idx = base + j * OWE_T;
            if (idx < n4) {
                f32x4 x = __builtin_nontemporal_load(&in4[idx]);
                i32x4 t = __builtin_nontemporal_load(&tg4[idx]);
                owe_process(x.x, t.x, s_tab, acc_num, acc_den);
                owe_process(x.y, t.y, s_tab, acc_num, acc_den);
                owe_process(x.z, t.z, s_tab, acc_num, acc_den);
                owe_process(x.w, t.w, s_tab, acc_num, acc_den);
            }
        }
    }

    // wave64 reduction
    #pragma unroll
    for (int off = 32; off > 0; off >>= 1) {
        acc_num += __shfl_down(acc_num, off);
        acc_den += __shfl_down(acc_den, off);
    }
    int lane = threadIdx.x & 63;
    int wid  = threadIdx.x >> 6;
    if (lane == 0) s_part[wid] = make_float2(acc_num, acc_den);
    __syncthreads();
    if (threadIdx.x == 0) {
        float n = 0.0f, d = 0.0f;
        #pragma unroll
        for (int w = 0; w < OWE_T / 64; ++w) { n += s_part[w].x; d += s_part[w].y; }
        partials[blockIdx.x] = make_float2(n, d);
    }
}

__global__ __launch_bounds__(256) void owe_final_kernel(
    const float2* __restrict__ partials, int nparts,
    const float*  __restrict__ input, const int* __restrict__ target,
    const float*  __restrict__ weight, const float* __restrict__ dist,
    int n, float* __restrict__ out)
{
    __shared__ double s_n[4], s_d[4];
    double nn = 0.0, dd = 0.0;
    for (int i = threadIdx.x; i < nparts; i += 256) {
        float2 p = partials[i];
        nn += (double)p.x;
        dd += (double)p.y;
    }
    #pragma unroll
    for (int off = 32; off > 0; off >>= 1) {
        nn += __shfl_down(nn, off);
        dd += __shfl_down(dd, off);
    }
    int lane = threadIdx.x & 63;
    int wid  = threadIdx.x >> 6;
    if (lane == 0) { s_n[wid] = nn; s_d[wid] = dd; }
    __syncthreads();
    if (threadIdx.x == 0) {
        double N = 0.0, D = 0.0;
        #pragma unroll
        for (int w = 0; w < 4; ++w) { N += s_n[w]; D += s_d[w]; }
        // leftover elements (n % 4 != 0) — none for N=2^24, kept for generality
        int rem_start = (n / 4) * 4;
        if (rem_start < n) {
            float d0 = dist[0], d1 = dist[1], d2 = dist[2], d3 = dist[3], d4 = dist[4];
            float cs1 = d0 + d1, cs2 = cs1 + d2, cs3 = cs2 + d3, cs4 = cs3 + d4;
            float inv = 1.0f / (2.0f * cs4 - d0 - d4);
            float pcnl[5] = {(2.0f * d0  - d0 - d0) * inv, (2.0f * cs1 - d1 - d0) * inv,
                             (2.0f * cs2 - d2 - d0) * inv, (2.0f * cs3 - d3 - d0) * inv,
                             (2.0f * cs4 - d4 - d0) * inv};
            for (int i = rem_start; i < n; ++i) {
                float xv = input[i];
                int   tv = target[i];
                float f  = floorf(xv);
                float v0 = f, v1 = f + 1.0f;
                int c0 = min(max((int)v0, 0), 4), c1 = min(max((int)v1, 0), 4);
                float pf = (v0 >= 0.0f && v0 <= 4.0f) ? pcnl[c0] : v0 * 0.25f;
                float pc = (v1 >= 0.0f && v1 <= 4.0f) ? pcnl[c1] : v1 * 0.25f;
                float ip = pf + (pc - pf) * (xv - f);
                float diff = ip - pcnl[tv];
                float w = weight[tv];
                N += (double)(diff * diff * w);
                D += (double)w;
            }
        }
        out[0] = (float)(N / D);
    }
}

extern "C" void kernel_launch(void* const* d_in, const int* in_sizes, int n_in,
                              void* d_out, int out_size, void* d_ws, size_t ws_size,
                              hipStream_t stream) {
    const float* input  = (const float*)d_in[0];
    const int*   target = (const int*)  d_in[1];
    const float* weight = (const float*)d_in[2];
    const float* dist   = (const float*)d_in[3];
    float*  out      = (float*)d_out;
    float2* partials = (float2*)d_ws;

    int n  = in_sizes[0];
    int n4 = n / 4;
    int grid = (n4 + OWE_T * OWE_J - 1) / (OWE_T * OWE_J);   // 4096 for N=2^24

    owe_reduce_kernel<<<grid, OWE_T, 0, stream>>>(
        (const f32x4*)input, (const i32x4*)target, weight, dist, partials, n4);
    owe_final_kernel<<<1, 256, 0, stream>>>(
        partials, grid, input, target, weight, dist, n, out);
}